// Round 9
// baseline (457.548 us; speedup 1.0000x reference)
//
#include <hip/hip_runtime.h>

// LoRA forward: out = x @ (A @ B * scale), split as:
//   Kernel Y: y[8192][8] = scale * (x @ A)     (x-read-bound, 134 MB)
//   Kernel O: out = y @ B                      (out-write-bound, 134 MB)
//
// R9 post-mortem: both kernels now < 79 us (displaced from top-5 by harness
// fills). Fill kernel calibration: 6.73 TB/s at VGPR=8, Occ 9% -> the memory
// pipe needs DEEP UNINTERRUPTED per-wave pipelines, not occupancy. Y's stream
// was chopped by 4 barriers (2 per 64 KB At half) + vmcnt drains.
// R10: Y stages the FULL At (128 KB LDS) ONCE with a single barrier;
// 1024-thread block, grid 256 = 1 block/CU, launch_bounds(1024,1) -> VGPR cap
// 128 (~75 live, no spill). After the barrier each wave streams 2 rows with
// 8-deep prefetch and zero further sync. O kernel byte-identical to R9.

#define DIM        4096
#define DIM4       1024        // float4 quads per row
#define RANK       8
#define LORA_SCALE 2.0f

typedef float f32x4 __attribute__((ext_vector_type(4)));

// ---------------- Kernel Y: y = scale * (x @ A) ----------------
#define YBLOCK     1024
#define YWAVES     16
#define YROWS      2                    // x-rows per wave
#define YRPB       (YWAVES * YROWS)     // 32 rows per block

__global__ __launch_bounds__(YBLOCK, 1) void lora_xa_kernel(
    const float* __restrict__ x,
    const float* __restrict__ A,
    float* __restrict__ y)
{
    __shared__ float sAt[RANK * DIM];   // 128 KiB: full transposed A

    const int tid  = threadIdx.x;
    const int wave = tid >> 6;
    const int lane = tid & 63;
    const size_t row0 = (size_t)blockIdx.x * YRPB;

    const float4* __restrict__ A4 = (const float4*)A;   // 8192 quads
    const float4* __restrict__ x4 = (const float4*)x;
    const float4* sAt4 = (const float4*)sAt;

    // ---- Stage full At once (8 coalesced quad-loads per thread) ----
#pragma unroll
    for (int q = 0; q < 8; ++q) {
        const int idx = tid + q * YBLOCK;          // 0..8191
        const float4 v = A4[idx];
        const int il = idx >> 1;                   // column 0..4095
        const int rq = (idx & 1) * 4;
        sAt[(rq + 0) * DIM + il] = v.x;
        sAt[(rq + 1) * DIM + il] = v.y;
        sAt[(rq + 2) * DIM + il] = v.z;
        sAt[(rq + 3) * DIM + il] = v.w;
    }
    __syncthreads();                               // the ONLY barrier

    // ---- Stream x: 2 rows/wave, 8-deep prefetch, no further sync ----
    float acc[YROWS][RANK];
#pragma unroll
    for (int m = 0; m < YROWS; ++m)
#pragma unroll
        for (int r = 0; r < RANK; ++r) acc[m][r] = 0.f;

#pragma unroll
    for (int pb = 0; pb < 4; ++pb) {
        float4 xq[4][YROWS];
#pragma unroll
        for (int p = 0; p < 4; ++p)
#pragma unroll
            for (int m = 0; m < YROWS; ++m)
                xq[p][m] = x4[(row0 + wave * YROWS + m) * DIM4
                              + (pb * 4 + p) * 64 + lane];
#pragma unroll
        for (int p = 0; p < 4; ++p) {
            const int il4 = (pb * 4 + p) * 64 + lane;   // quad col 0..1023
#pragma unroll
            for (int r = 0; r < RANK; ++r) {
                const float4 a = sAt4[r * DIM4 + il4];  // 2-way = free
#pragma unroll
                for (int m = 0; m < YROWS; ++m)
                    acc[m][r] += xq[p][m].x * a.x + xq[p][m].y * a.y
                               + xq[p][m].z * a.z + xq[p][m].w * a.w;
            }
        }
    }

    // ---- Butterfly reduce per row; lane<8 writes y[row][lane] ----
#pragma unroll
    for (int m = 0; m < YROWS; ++m) {
        float tval = 0.f;
#pragma unroll
        for (int r = 0; r < RANK; ++r) {
            float v = acc[m][r];
#pragma unroll
            for (int off = 1; off < 64; off <<= 1)
                v += __shfl_xor(v, off, 64);
            v *= LORA_SCALE;
            if (lane == r) tval = v;
        }
        if (lane < RANK)
            y[(row0 + wave * YROWS + m) * RANK + lane] = tval;
    }
}

// ---------------- Kernel O: out = y @ B (byte-identical to R9) ----------------
#define OBLOCK     256
#define OWAVES     4
#define OROWS      16          // rows per block
#define OCOLQ      256         // col-quads per block (= 1024 cols)

__global__ __launch_bounds__(OBLOCK, 6) void lora_yb_kernel(
    const float* __restrict__ y,
    const float* __restrict__ B,
    float* __restrict__ out)
{
    const int swz    = (blockIdx.x & 7) * 256 + (blockIdx.x >> 3);
    const int colblk = swz >> 9;          // 0..3
    const int rowblk = swz & 511;         // 0..511

    const int tid  = threadIdx.x;
    const int wave = tid >> 6;
    const int lane = tid & 63;
    const size_t row0 = (size_t)rowblk * OROWS;
    const int i4c = colblk * OCOLQ + wave * 64 + lane;   // 0..1023

    const float4* __restrict__ B4 = (const float4*)B;
    const float4* __restrict__ y4 = (const float4*)y;    // y[row] = 2 quads
    f32x4* __restrict__ out4 = (f32x4*)out;

    float4 b[RANK];
#pragma unroll
    for (int r = 0; r < RANK; ++r)
        b[r] = B4[r * DIM4 + i4c];        // coalesced; L2-hot after first touch

#pragma unroll 4
    for (int m = 0; m < OROWS; ++m) {
        const float4 t0 = y4[(row0 + m) * 2 + 0];   // uniform -> broadcast
        const float4 t1 = y4[(row0 + m) * 2 + 1];
        float4 o;
        o.x = t0.x * b[0].x; o.y = t0.x * b[0].y;
        o.z = t0.x * b[0].z; o.w = t0.x * b[0].w;
        o.x += t0.y * b[1].x; o.y += t0.y * b[1].y;
        o.z += t0.y * b[1].z; o.w += t0.y * b[1].w;
        o.x += t0.z * b[2].x; o.y += t0.z * b[2].y;
        o.z += t0.z * b[2].z; o.w += t0.z * b[2].w;
        o.x += t0.w * b[3].x; o.y += t0.w * b[3].y;
        o.z += t0.w * b[3].z; o.w += t0.w * b[3].w;
        o.x += t1.x * b[4].x; o.y += t1.x * b[4].y;
        o.z += t1.x * b[4].z; o.w += t1.x * b[4].w;
        o.x += t1.y * b[5].x; o.y += t1.y * b[5].y;
        o.z += t1.y * b[5].z; o.w += t1.y * b[5].w;
        o.x += t1.z * b[6].x; o.y += t1.z * b[6].y;
        o.z += t1.z * b[6].z; o.w += t1.z * b[6].w;
        o.x += t1.w * b[7].x; o.y += t1.w * b[7].y;
        o.z += t1.w * b[7].z; o.w += t1.w * b[7].w;
        f32x4 ov;
        ov.x = o.x; ov.y = o.y; ov.z = o.z; ov.w = o.w;
        __builtin_nontemporal_store(ov, &out4[(row0 + m) * DIM4 + i4c]);
    }
}

extern "C" void kernel_launch(void* const* d_in, const int* in_sizes, int n_in,
                              void* d_out, int out_size, void* d_ws, size_t ws_size,
                              hipStream_t stream) {
    const float* x = (const float*)d_in[0];   // [4, 2048, 4096]
    const float* A = (const float*)d_in[1];   // [4096, 8]
    const float* B = (const float*)d_in[2];   // [8, 4096]
    float* out = (float*)d_out;
    float* y   = (float*)d_ws;                // 8192*8 floats = 256 KiB

    const int rows = in_sizes[0] / DIM;       // 8192

    lora_xa_kernel<<<rows / YRPB, YBLOCK, 0, stream>>>(x, A, y);
    lora_yb_kernel<<<(rows / OROWS) * (DIM4 / OCOLQ), OBLOCK, 0, stream>>>(y, B, out);
}